// Round 6
// baseline (154.941 us; speedup 1.0000x reference)
//
#include <hip/hip_runtime.h>
#include <hip/hip_bf16.h>

namespace {

constexpr int S_LEN = 2048;
constexpr int DH    = 128;
constexpr int KVB   = 64;             // kv rows per tile
constexpr int QT    = 128;            // q rows per block (4 q-chunks x 32)
constexpr int NQT   = S_LEN / QT;     // 16 strips
constexpr int NKT   = S_LEN / KVB;    // 32 kv tiles
constexpr int TILE_SH = KVB * DH;     // 8192 shorts = 16 KB per tile image

typedef __attribute__((ext_vector_type(4)))  float  f32x4;
typedef __attribute__((ext_vector_type(16))) float  f32x16;
typedef __attribute__((ext_vector_type(8)))  short  short8;
typedef __attribute__((ext_vector_type(8)))  __bf16 bf16x8;

typedef __attribute__((address_space(1))) const unsigned int gu32;
typedef __attribute__((address_space(3))) unsigned int       lu32;

__device__ __forceinline__ unsigned pk2(float a, float b) {
    unsigned short lo = __builtin_bit_cast(unsigned short, __float2bfloat16(a));
    unsigned short hh = __builtin_bit_cast(unsigned short, __float2bfloat16(b));
    return (unsigned)lo | ((unsigned)hh << 16);
}
__device__ __forceinline__ f32x16 mfma32(short8 a, short8 b, f32x16 c) {
    return __builtin_amdgcn_mfma_f32_32x32x16_bf16(
        __builtin_bit_cast(bf16x8, a), __builtin_bit_cast(bf16x8, b), c, 0, 0, 0);
}
__device__ __forceinline__ f32x16 zero16() {
    f32x16 z;
    #pragma unroll
    for (int i = 0; i < 16; ++i) z[i] = 0.f;
    return z;
}
__device__ __forceinline__ short8 mk8(unsigned a, unsigned b, unsigned c, unsigned d) {
    uint4 u; u.x = a; u.y = b; u.z = c; u.w = d;
    return __builtin_bit_cast(short8, u);
}

// ---------------- pre-pass: fp32 K,V -> bf16 swizzled LDS tile images in ws --------
// K image:  e = (row*DH + col) ^ ((row&7)<<3), holds K[row][col] (bf16)
// V image:  e = (d*KVB + k)  ^ ((d&7)<<3),    holds V[k][d]     (bf16, transposed)
__global__ void __launch_bounds__(256)
prep_kv(const float* __restrict__ Kp, const float* __restrict__ Vp,
        short* __restrict__ wsK, short* __restrict__ wsV)
{
    const int blk = blockIdx.x;          // 0..1023 = bh*32 + kt
    const int bh  = blk >> 5;
    const int kt  = blk & 31;
    const int tid = threadIdx.x;

    const float* Ks = Kp + (size_t)bh * (S_LEN * DH) + (size_t)kt * KVB * DH;
    const float* Vs = Vp + (size_t)bh * (S_LEN * DH) + (size_t)kt * KVB * DH;
    short* dK = wsK + (size_t)blk * TILE_SH;
    short* dV = wsV + (size_t)blk * TILE_SH;

    #pragma unroll
    for (int i = 0; i < 4; ++i) {
        const int e = (tid + 256 * i) * 8;      // dest short index (8 per thread)
        // ---- K ----
        {
            const int row  = e >> 7;
            const int scol = (e & 127) ^ ((row & 7) << 3);
            f32x4 a = *reinterpret_cast<const f32x4*>(Ks + row * DH + scol);
            f32x4 b = *reinterpret_cast<const f32x4*>(Ks + row * DH + scol + 4);
            uint4 u;
            u.x = pk2(a[0], a[1]); u.y = pk2(a[2], a[3]);
            u.z = pk2(b[0], b[1]); u.w = pk2(b[2], b[3]);
            *reinterpret_cast<uint4*>(&dK[e]) = u;
        }
        // ---- V^T ----
        {
            const int d  = e >> 6;
            const int kb = (e & 63) ^ ((d & 7) << 3);
            float t[8];
            #pragma unroll
            for (int m2 = 0; m2 < 8; ++m2)
                t[m2] = Vs[(size_t)(kb + m2) * DH + d];
            uint4 u;
            u.x = pk2(t[0], t[1]); u.y = pk2(t[2], t[3]);
            u.z = pk2(t[4], t[5]); u.w = pk2(t[6], t[7]);
            *reinterpret_cast<uint4*>(&dV[e]) = u;
        }
    }
}

// ---------------- main attention kernel ----------------
// 8 waves: wave = (q-chunk qc=w&3, k-half h=w>>2). Each wave computes a 32q x 32k
// slice of every tile; per-wave online-softmax states merged at the end in LDS.
__global__ void __launch_bounds__(512, 4)
attn_fwd(const float* __restrict__ Qp, const short* __restrict__ wsK,
         const short* __restrict__ wsV, float* __restrict__ Op)
{
    __shared__ __align__(16) short ksm[2][TILE_SH];   // K  [64][128] swizzled (32 KB)
    __shared__ __align__(16) short vtm[2][TILE_SH];   // V^T[128][64] swizzled (32 KB)

    const int bh  = blockIdx.x;        // x = bh -> XCD = bh&7: all strips of a bh
    const int qt  = blockIdx.y;        //   share one XCD's L2, advance in lockstep
    const int tid = threadIdx.x;
    const int w   = tid >> 6;
    const int l   = tid & 63;
    const int r31 = l & 31;
    const int hi  = l >> 5;
    const int qc  = w & 3;             // q-chunk 0..3
    const int h   = w >> 2;            // k-half 0..1

    const size_t base = (size_t)bh * (S_LEN * DH);
    const short* Kt = wsK + (size_t)bh * NKT * TILE_SH;
    const short* Vt = wsV + (size_t)bh * NKT * TILE_SH;

    const int qw = qt * QT + 32 * qc;      // wave's first q row
    const int qg = qw + r31;               // lane's q row
    const int nkt = (qt + 1) * (QT / KVB);

    const float QS = 0.08838834764831845f * 1.4426950408889634f; // 1/sqrt(128)*log2(e)

    // ---- async staging: 512 threads, 4 x global_load_lds(16B) per thread/tile ----
    auto stage = [&](int kt, int b) {
        #pragma unroll
        for (int j = 0; j < 2; ++j) {
            const int off = j * 4096 + w * 512;          // wave-uniform LDS offset
            __builtin_amdgcn_global_load_lds(
                (gu32*)(Kt + (size_t)kt * TILE_SH + off + l * 8),
                (lu32*)(&ksm[b][off]), 16, 0, 0);
            __builtin_amdgcn_global_load_lds(
                (gu32*)(Vt + (size_t)kt * TILE_SH + off + l * 8),
                (lu32*)(&vtm[b][off]), 16, 0, 0);
        }
    };
    auto ldK = [&](const short* ks, int row, int col) -> short8 {
        return *reinterpret_cast<const short8*>(&ks[(row * DH + col) ^ ((row & 7) << 3)]);
    };
    auto ldV = [&](const short* vt, int vr, int col) -> short8 {
        return *reinterpret_cast<const short8*>(&vt[(vr * KVB + col) ^ ((vr & 7) << 3)]);
    };

    // ---- Q fragments (B-operand: col=q=r31, k-elem=8hi+j per 16-d slice) ----
    short8 qb[8];
    {
        const float* qrow = Qp + base + (size_t)qg * DH + 8 * hi;
        #pragma unroll
        for (int t = 0; t < 8; ++t) {
            f32x4 f0 = *reinterpret_cast<const f32x4*>(qrow + 16 * t);
            f32x4 f1 = *reinterpret_cast<const f32x4*>(qrow + 16 * t + 4);
            qb[t] = mk8(pk2(f0[0] * QS, f0[1] * QS), pk2(f0[2] * QS, f0[3] * QS),
                        pk2(f1[0] * QS, f1[1] * QS), pk2(f1[2] * QS, f1[3] * QS));
        }
    }

    f32x16 acc_o[4];
    #pragma unroll
    for (int i = 0; i < 4; ++i) acc_o[i] = zero16();
    float m_run = -1e30f, l_run = 0.f;

    // ---- prologue ----
    stage(0, 0);
    asm volatile("s_waitcnt vmcnt(0)" ::: "memory");
    __syncthreads();
    int cur = 0;

    for (int kt = 0; kt < nkt; ++kt) {
        const int k0 = kt * KVB;
        const bool more = (kt + 1 < nkt);
        if (more) stage(kt + 1, cur ^ 1);    // prefetch next tile under compute

        const int kbase = k0 + 32 * h;       // this wave's 32-k slice start
        if (kbase <= qw) {
            const short* ks = ksm[cur];
            const short* vt = vtm[cur];

            // ---- QK^T (swapped): lane q=r31, k=kbase+crow(rg,hi) ----
            f32x16 s = zero16();
            __builtin_amdgcn_s_setprio(1);
            #pragma unroll
            for (int t = 0; t < 8; ++t)
                s = mfma32(ldK(ks, r31 + 32 * h, 16 * t + 8 * hi), qb[t], s);
            __builtin_amdgcn_s_setprio(0);

            // ---- causal mask (diagonal slice only: kbase == qw) ----
            if (kbase == qw) {
                #pragma unroll
                for (int rg = 0; rg < 16; ++rg) {
                    const int kl = (rg & 3) + 8 * (rg >> 2) + 4 * hi;
                    if (kl > r31) s[rg] = -3.0e38f;
                }
            }

            // ---- online softmax (in-register, exp2 domain, defer-max T13) ----
            float tm[16];
            #pragma unroll
            for (int i = 0; i < 16; ++i) tm[i] = s[i];
            #pragma unroll
            for (int st = 8; st > 0; st >>= 1)
                #pragma unroll
                for (int i = 0; i < st; ++i) tm[i] = fmaxf(tm[i], tm[i + st]);
            const float mt = fmaxf(tm[0], __shfl_xor(tm[0], 32));

            float mn = m_run;
            if (!__all(mt <= m_run + 8.0f)) {
                mn = fmaxf(m_run, mt);
                const float al = exp2f(m_run - mn);
                m_run = mn;
                l_run *= al;
                #pragma unroll
                for (int d0 = 0; d0 < 4; ++d0)
                    #pragma unroll
                    for (int i = 0; i < 16; ++i) acc_o[d0][i] *= al;
            }

            #pragma unroll
            for (int i = 0; i < 16; ++i) s[i] = exp2f(s[i] - mn);
            float ts[16];
            #pragma unroll
            for (int i = 0; i < 16; ++i) ts[i] = s[i];
            #pragma unroll
            for (int st = 8; st > 0; st >>= 1)
                #pragma unroll
                for (int i = 0; i < st; ++i) ts[i] += ts[i + st];
            l_run += ts[0] + __shfl_xor(ts[0], 32);

            // ---- P -> bf16 B-fragments (cvt_pk + permlane32_swap T12) ----
            short8 pbs[2];
            #pragma unroll
            for (int h2 = 0; h2 < 2; ++h2) {
                unsigned a1 = pk2(s[8 * h2 + 0], s[8 * h2 + 1]);
                unsigned a2 = pk2(s[8 * h2 + 2], s[8 * h2 + 3]);
                unsigned b1 = pk2(s[8 * h2 + 4], s[8 * h2 + 5]);
                unsigned b2 = pk2(s[8 * h2 + 6], s[8 * h2 + 7]);
                asm volatile("v_permlane32_swap_b32 %0, %1" : "+v"(a1), "+v"(b1));
                asm volatile("v_permlane32_swap_b32 %0, %1" : "+v"(a2), "+v"(b2));
                uint4 u; u.x = a1; u.y = a2; u.z = b1; u.w = b2;
                pbs[h2] = __builtin_bit_cast(short8, u);
            }

            // ---- PV: O^T = V^T x P^T (this wave's 32-k slice) ----
            __builtin_amdgcn_s_setprio(1);
            #pragma unroll
            for (int d0 = 0; d0 < 4; ++d0) {
                const int vr = 32 * d0 + r31;
                acc_o[d0] = mfma32(ldV(vt, vr, 32 * h + 8 * hi), pbs[0], acc_o[d0]);
                acc_o[d0] = mfma32(ldV(vt, vr, 32 * h + 16 + 8 * hi), pbs[1], acc_o[d0]);
            }
            __builtin_amdgcn_s_setprio(0);
        }

        if (more) {
            asm volatile("s_waitcnt vmcnt(0)" ::: "memory");
            __syncthreads();                 // one barrier per tile
            cur ^= 1;
        }
    }

    // ---- merge k-half partial states (exact fp32, via LDS) ----
    __syncthreads();                         // tile buffers now reusable
    float* xml = (float*)&vtm[0][0];         // [4 chunks][64 lanes][2]
    if (h == 1) {
        xml[(qc * 64 + l) * 2 + 0] = m_run;
        xml[(qc * 64 + l) * 2 + 1] = l_run;
    }
    __syncthreads();
    float sa = 1.f, sb = 0.f;
    if (h == 0) {
        const float mB = xml[(qc * 64 + l) * 2 + 0];
        const float lB = xml[(qc * 64 + l) * 2 + 1];
        const float mm = fmaxf(m_run, mB);
        sa = exp2f(m_run - mm);
        sb = exp2f(mB - mm);
        l_run = l_run * sa + lB * sb;
    }
    float* xa = (float*)&ksm[0][0];          // 32 KB: [4 chunks][32 regs][64 lanes]
    #pragma unroll
    for (int r = 0; r < 2; ++r) {            // two rounds: d0 {0,1}, then {2,3}
        __syncthreads();
        if (h == 1) {
            #pragma unroll
            for (int dd = 0; dd < 2; ++dd)
                #pragma unroll
                for (int i = 0; i < 16; ++i)
                    xa[qc * 2048 + (dd * 16 + i) * 64 + l] = acc_o[2 * r + dd][i];
        }
        __syncthreads();
        if (h == 0) {
            #pragma unroll
            for (int dd = 0; dd < 2; ++dd)
                #pragma unroll
                for (int i = 0; i < 16; ++i)
                    acc_o[2 * r + dd][i] = acc_o[2 * r + dd][i] * sa
                        + xa[qc * 2048 + (dd * 16 + i) * 64 + l] * sb;
        }
    }

    // ---- epilogue: normalize, store fp32 (h==0 waves own the output) ----
    if (h == 0) {
        const float rl = 1.0f / l_run;
        float* orow = Op + base + (size_t)qg * DH;
        #pragma unroll
        for (int d0 = 0; d0 < 4; ++d0) {
            #pragma unroll
            for (int rg = 0; rg < 4; ++rg) {
                f32x4 v;
                v[0] = acc_o[d0][4 * rg + 0] * rl;
                v[1] = acc_o[d0][4 * rg + 1] * rl;
                v[2] = acc_o[d0][4 * rg + 2] * rl;
                v[3] = acc_o[d0][4 * rg + 3] * rl;
                *reinterpret_cast<f32x4*>(orow + 32 * d0 + 8 * rg + 4 * hi) = v;
            }
        }
    }
}

} // namespace

extern "C" void kernel_launch(void* const* d_in, const int* in_sizes, int n_in,
                              void* d_out, int out_size, void* d_ws, size_t ws_size,
                              hipStream_t stream)
{
    const float* Q = (const float*)d_in[0];
    const float* K = (const float*)d_in[1];
    const float* V = (const float*)d_in[2];
    float* O = (float*)d_out;

    short* wsK = (short*)d_ws;                          // 32*32 tiles * 16 KB
    short* wsV = wsK + (size_t)32 * NKT * TILE_SH;      // ws >= 33.6 MB

    hipLaunchKernelGGL(prep_kv, dim3(32 * NKT), dim3(256), 0, stream, K, V, wsK, wsV);
    hipLaunchKernelGGL(attn_fwd, dim3(32, NQT), dim3(512), 0, stream, Q, wsK, wsV, O);
}

// Round 7
// 104.013 us; speedup vs baseline: 1.4896x; 1.4896x over previous
//
#include <hip/hip_runtime.h>
#include <hip/hip_bf16.h>

namespace {

constexpr int S_LEN = 2048;
constexpr int DH    = 128;
constexpr int KVB   = 64;             // kv rows per tile
constexpr int QT    = 128;            // q rows per block (4 waves x 32)
constexpr int NQT   = S_LEN / QT;     // 16 strips
constexpr int NKT   = S_LEN / KVB;    // 32 kv tiles
constexpr int TILE_SH = KVB * DH;     // 8192 shorts = 16 KB per tile image

typedef __attribute__((ext_vector_type(4)))  float  f32x4;
typedef __attribute__((ext_vector_type(16))) float  f32x16;
typedef __attribute__((ext_vector_type(8)))  short  short8;
typedef __attribute__((ext_vector_type(8)))  __bf16 bf16x8;

typedef __attribute__((address_space(1))) const unsigned int gu32;
typedef __attribute__((address_space(3))) unsigned int       lu32;

__device__ __forceinline__ unsigned pk2(float a, float b) {
    unsigned short lo = __builtin_bit_cast(unsigned short, __float2bfloat16(a));
    unsigned short hh = __builtin_bit_cast(unsigned short, __float2bfloat16(b));
    return (unsigned)lo | ((unsigned)hh << 16);
}
__device__ __forceinline__ f32x16 mfma32(short8 a, short8 b, f32x16 c) {
    return __builtin_amdgcn_mfma_f32_32x32x16_bf16(
        __builtin_bit_cast(bf16x8, a), __builtin_bit_cast(bf16x8, b), c, 0, 0, 0);
}
__device__ __forceinline__ f32x16 zero16() {
    f32x16 z;
    #pragma unroll
    for (int i = 0; i < 16; ++i) z[i] = 0.f;
    return z;
}
__device__ __forceinline__ short8 mk8(unsigned a, unsigned b, unsigned c, unsigned d) {
    uint4 u; u.x = a; u.y = b; u.z = c; u.w = d;
    return __builtin_bit_cast(short8, u);
}

// ---------------- pre-pass: fp32 K,V -> bf16 swizzled LDS tile images in ws --------
// K image:  e = (row*DH + col) ^ ((row&7)<<3), holds K[row][col] (bf16)
// V image:  e = (d*KVB + k)  ^ ((d&7)<<3),    holds V[k][d]     (bf16, transposed)
__global__ void __launch_bounds__(256)
prep_kv(const float* __restrict__ Kp, const float* __restrict__ Vp,
        short* __restrict__ wsK, short* __restrict__ wsV)
{
    const int blk = blockIdx.x;          // 0..1023 = bh*32 + kt
    const int bh  = blk >> 5;
    const int kt  = blk & 31;
    const int tid = threadIdx.x;

    const float* Ks = Kp + (size_t)bh * (S_LEN * DH) + (size_t)kt * KVB * DH;
    const float* Vs = Vp + (size_t)bh * (S_LEN * DH) + (size_t)kt * KVB * DH;
    short* dK = wsK + (size_t)blk * TILE_SH;
    short* dV = wsV + (size_t)blk * TILE_SH;

    #pragma unroll
    for (int i = 0; i < 4; ++i) {
        const int e = (tid + 256 * i) * 8;      // dest short index (8 per thread)
        // ---- K ----
        {
            const int row  = e >> 7;
            const int scol = (e & 127) ^ ((row & 7) << 3);
            f32x4 a = *reinterpret_cast<const f32x4*>(Ks + row * DH + scol);
            f32x4 b = *reinterpret_cast<const f32x4*>(Ks + row * DH + scol + 4);
            uint4 u;
            u.x = pk2(a[0], a[1]); u.y = pk2(a[2], a[3]);
            u.z = pk2(b[0], b[1]); u.w = pk2(b[2], b[3]);
            *reinterpret_cast<uint4*>(&dK[e]) = u;
        }
        // ---- V^T ----
        {
            const int d  = e >> 6;
            const int kb = (e & 63) ^ ((d & 7) << 3);
            float t[8];
            #pragma unroll
            for (int m2 = 0; m2 < 8; ++m2)
                t[m2] = Vs[(size_t)(kb + m2) * DH + d];
            uint4 u;
            u.x = pk2(t[0], t[1]); u.y = pk2(t[2], t[3]);
            u.z = pk2(t[4], t[5]); u.w = pk2(t[6], t[7]);
            *reinterpret_cast<uint4*>(&dV[e]) = u;
        }
    }
}

// ---------------- main attention kernel ----------------
__global__ void __launch_bounds__(256, 2)
attn_fwd(const float* __restrict__ Qp, const short* __restrict__ wsK,
         const short* __restrict__ wsV, float* __restrict__ Op)
{
    __shared__ __align__(16) short ksm[2][TILE_SH];   // K  [64][128] swizzled
    __shared__ __align__(16) short vtm[2][TILE_SH];   // V^T[128][64] swizzled

    // ---- balanced mapping: co-resident pair (i, i+256) -> same bh, qt j & 15-j ----
    // per-CU work = 2(j+1) + 2(16-j) = 34 tiles (constant); same bh -> shared L2
    // tile images; all strips of bh land on XCD bh%8.
    const int i0  = blockIdx.x;
    const int bh  = i0 & 31;
    const int j   = (i0 >> 5) & 7;
    const int qt  = (i0 >> 8) ? (NQT - 1 - j) : j;

    const int tid = threadIdx.x;
    const int w   = tid >> 6;
    const int l   = tid & 63;
    const int r31 = l & 31;
    const int hi  = l >> 5;

    const size_t base = (size_t)bh * (S_LEN * DH);
    const short* Kt = wsK + (size_t)bh * NKT * TILE_SH;
    const short* Vt = wsV + (size_t)bh * NKT * TILE_SH;

    const int qw = qt * QT + 32 * w;       // wave's first q row
    const int qg = qw + r31;               // lane's q row
    const int nkt = (qt + 1) * (QT / KVB);

    const float QS = 0.08838834764831845f * 1.4426950408889634f; // 1/sqrt(128)*log2(e)

    // ---- async staging: each wave loads its 4KB quarter of K and V images ----
    auto stage = [&](int kt, int b) {
        const short* gk = Kt + (size_t)kt * TILE_SH + w * 2048 + l * 8;
        const short* gv = Vt + (size_t)kt * TILE_SH + w * 2048 + l * 8;
        short* lk = &ksm[b][w * 2048];
        short* lv = &vtm[b][w * 2048];
        #pragma unroll
        for (int j2 = 0; j2 < 4; ++j2) {
            __builtin_amdgcn_global_load_lds((gu32*)(gk + j2 * 512), (lu32*)(lk + j2 * 512), 16, 0, 0);
            __builtin_amdgcn_global_load_lds((gu32*)(gv + j2 * 512), (lu32*)(lv + j2 * 512), 16, 0, 0);
        }
    };
    auto ldK = [&](const short* ks, int row, int col) -> short8 {
        return *reinterpret_cast<const short8*>(&ks[(row * DH + col) ^ ((row & 7) << 3)]);
    };
    auto ldV = [&](const short* vt, int vr, int col) -> short8 {
        return *reinterpret_cast<const short8*>(&vt[(vr * KVB + col) ^ ((vr & 7) << 3)]);
    };

    // ---- Q fragments (B-operand: col=q=r31, k-elem=8hi+j per 16-d slice) ----
    short8 qb[8];
    {
        const float* qrow = Qp + base + (size_t)qg * DH + 8 * hi;
        #pragma unroll
        for (int t = 0; t < 8; ++t) {
            f32x4 f0 = *reinterpret_cast<const f32x4*>(qrow + 16 * t);
            f32x4 f1 = *reinterpret_cast<const f32x4*>(qrow + 16 * t + 4);
            qb[t] = mk8(pk2(f0[0] * QS, f0[1] * QS), pk2(f0[2] * QS, f0[3] * QS),
                        pk2(f1[0] * QS, f1[1] * QS), pk2(f1[2] * QS, f1[3] * QS));
        }
    }

    f32x16 acc_o[4];
    #pragma unroll
    for (int i = 0; i < 4; ++i) acc_o[i] = zero16();
    float m_run = -1e30f, l_run = 0.f;

    // ---- prologue ----
    stage(0, 0);
    asm volatile("s_waitcnt vmcnt(0)" ::: "memory");
    __syncthreads();
    int cur = 0;

    for (int kt = 0; kt < nkt; ++kt) {
        const int k0 = kt * KVB;
        const bool more = (kt + 1 < nkt);
        if (more) stage(kt + 1, cur ^ 1);    // overlap HBM/L2 latency with compute

        if (k0 <= qw) {
            const bool useS1 = (k0 < qw);
            const short* ks = ksm[cur];
            const short* vt = vtm[cur];

            // ---- QK^T (swapped): lane q=r31, k=crow(rg,hi) (+32 in s1) ----
            f32x16 s0 = zero16(), s1 = zero16();
            __builtin_amdgcn_s_setprio(1);
            #pragma unroll
            for (int t = 0; t < 8; ++t)
                s0 = mfma32(ldK(ks, r31, 16 * t + 8 * hi), qb[t], s0);
            if (useS1) {
                #pragma unroll
                for (int t = 0; t < 8; ++t)
                    s1 = mfma32(ldK(ks, r31 + 32, 16 * t + 8 * hi), qb[t], s1);
            }
            __builtin_amdgcn_s_setprio(0);

            // ---- causal mask (diagonal tiles only) ----
            if (k0 == qw) {
                #pragma unroll
                for (int rg = 0; rg < 16; ++rg) {
                    const int kl = (rg & 3) + 8 * (rg >> 2) + 4 * hi;
                    if (k0 + kl > qg) s0[rg] = -3.0e38f;
                }
            }
            if (useS1 && (k0 + 32 == qw)) {
                #pragma unroll
                for (int rg = 0; rg < 16; ++rg) {
                    const int kl = (rg & 3) + 8 * (rg >> 2) + 4 * hi;
                    if (k0 + 32 + kl > qg) s1[rg] = -3.0e38f;
                }
            }

            // ---- online softmax (in-register, exp2 domain, defer-max T13) ----
            float tm[16];
            #pragma unroll
            for (int i = 0; i < 16; ++i) tm[i] = useS1 ? fmaxf(s0[i], s1[i]) : s0[i];
            #pragma unroll
            for (int st = 8; st > 0; st >>= 1)
                #pragma unroll
                for (int i = 0; i < st; ++i) tm[i] = fmaxf(tm[i], tm[i + st]);
            const float mt = fmaxf(tm[0], __shfl_xor(tm[0], 32));

            float mn = m_run;
            if (!__all(mt <= m_run + 8.0f)) {
                mn = fmaxf(m_run, mt);
                const float al = exp2f(m_run - mn);
                m_run = mn;
                l_run *= al;
                #pragma unroll
                for (int d0 = 0; d0 < 4; ++d0)
                    #pragma unroll
                    for (int i = 0; i < 16; ++i) acc_o[d0][i] *= al;
            }

            #pragma unroll
            for (int i = 0; i < 16; ++i) s0[i] = exp2f(s0[i] - mn);
            if (useS1) {
                #pragma unroll
                for (int i = 0; i < 16; ++i) s1[i] = exp2f(s1[i] - mn);
            }
            float ts[16];
            #pragma unroll
            for (int i = 0; i < 16; ++i) ts[i] = useS1 ? (s0[i] + s1[i]) : s0[i];
            #pragma unroll
            for (int st = 8; st > 0; st >>= 1)
                #pragma unroll
                for (int i = 0; i < st; ++i) ts[i] += ts[i + st];
            l_run += ts[0] + __shfl_xor(ts[0], 32);

            // ---- P -> bf16 B-fragments (cvt_pk + permlane32_swap T12) ----
            short8 pbs[4];
            auto mkpb = [&](const f32x16& s, short8* out) {
                #pragma unroll
                for (int h = 0; h < 2; ++h) {
                    unsigned a1 = pk2(s[8 * h + 0], s[8 * h + 1]);
                    unsigned a2 = pk2(s[8 * h + 2], s[8 * h + 3]);
                    unsigned b1 = pk2(s[8 * h + 4], s[8 * h + 5]);
                    unsigned b2 = pk2(s[8 * h + 6], s[8 * h + 7]);
                    asm volatile("v_permlane32_swap_b32 %0, %1" : "+v"(a1), "+v"(b1));
                    asm volatile("v_permlane32_swap_b32 %0, %1" : "+v"(a2), "+v"(b2));
                    uint4 u; u.x = a1; u.y = a2; u.z = b1; u.w = b2;
                    out[h] = __builtin_bit_cast(short8, u);
                }
            };
            mkpb(s0, &pbs[0]);
            if (useS1) mkpb(s1, &pbs[2]);

            // ---- PV: O^T = V^T x P^T ----
            __builtin_amdgcn_s_setprio(1);
            #pragma unroll
            for (int d0 = 0; d0 < 4; ++d0) {
                const int vr = 32 * d0 + r31;
                acc_o[d0] = mfma32(ldV(vt, vr, 8 * hi), pbs[0], acc_o[d0]);
                acc_o[d0] = mfma32(ldV(vt, vr, 16 + 8 * hi), pbs[1], acc_o[d0]);
            }
            if (useS1) {
                #pragma unroll
                for (int d0 = 0; d0 < 4; ++d0) {
                    const int vr = 32 * d0 + r31;
                    acc_o[d0] = mfma32(ldV(vt, vr, 32 + 8 * hi), pbs[2], acc_o[d0]);
                    acc_o[d0] = mfma32(ldV(vt, vr, 48 + 8 * hi), pbs[3], acc_o[d0]);
                }
            }
            __builtin_amdgcn_s_setprio(0);
        }

        if (more) {
            asm volatile("s_waitcnt vmcnt(0)" ::: "memory");
            __syncthreads();                 // one barrier per tile
            cur ^= 1;
        }
    }

    // ---- epilogue: normalize, store fp32 ----
    const float rl = 1.0f / l_run;
    float* orow = Op + base + (size_t)qg * DH;
    #pragma unroll
    for (int d0 = 0; d0 < 4; ++d0) {
        #pragma unroll
        for (int rg = 0; rg < 4; ++rg) {
            f32x4 v;
            v[0] = acc_o[d0][4 * rg + 0] * rl;
            v[1] = acc_o[d0][4 * rg + 1] * rl;
            v[2] = acc_o[d0][4 * rg + 2] * rl;
            v[3] = acc_o[d0][4 * rg + 3] * rl;
            *reinterpret_cast<f32x4*>(orow + 32 * d0 + 8 * rg + 4 * hi) = v;
        }
    }
}

} // namespace

extern "C" void kernel_launch(void* const* d_in, const int* in_sizes, int n_in,
                              void* d_out, int out_size, void* d_ws, size_t ws_size,
                              hipStream_t stream)
{
    const float* Q = (const float*)d_in[0];
    const float* K = (const float*)d_in[1];
    const float* V = (const float*)d_in[2];
    float* O = (float*)d_out;

    short* wsK = (short*)d_ws;                          // 32*32 tiles * 16 KB
    short* wsV = wsK + (size_t)32 * NKT * TILE_SH;      // ws >= 33.6 MB

    hipLaunchKernelGGL(prep_kv, dim3(32 * NKT), dim3(256), 0, stream, K, V, wsK, wsV);
    hipLaunchKernelGGL(attn_fwd, dim3(512), dim3(256), 0, stream, Q, wsK, wsV, O);
}

// Round 8
// 103.852 us; speedup vs baseline: 1.4919x; 1.0016x over previous
//
#include <hip/hip_runtime.h>
#include <hip/hip_bf16.h>

namespace {

constexpr int S_LEN = 2048;
constexpr int DH    = 128;
constexpr int KVB   = 64;             // kv rows per tile
constexpr int QT    = 128;            // q rows per strip (4 waves x 32)
constexpr int NQT   = S_LEN / QT;     // 16 strips
constexpr int NKT   = S_LEN / KVB;    // 32 kv tiles
constexpr int TILE_SH = KVB * DH;     // 8192 shorts = 16 KB per tile image

typedef __attribute__((ext_vector_type(4)))  float  f32x4;
typedef __attribute__((ext_vector_type(16))) float  f32x16;
typedef __attribute__((ext_vector_type(8)))  short  short8;
typedef __attribute__((ext_vector_type(8)))  __bf16 bf16x8;

typedef __attribute__((address_space(1))) const unsigned int gu32;
typedef __attribute__((address_space(3))) unsigned int       lu32;

__device__ __forceinline__ unsigned pk2(float a, float b) {
    unsigned short lo = __builtin_bit_cast(unsigned short, __float2bfloat16(a));
    unsigned short hh = __builtin_bit_cast(unsigned short, __float2bfloat16(b));
    return (unsigned)lo | ((unsigned)hh << 16);
}
__device__ __forceinline__ f32x16 mfma32(short8 a, short8 b, f32x16 c) {
    return __builtin_amdgcn_mfma_f32_32x32x16_bf16(
        __builtin_bit_cast(bf16x8, a), __builtin_bit_cast(bf16x8, b), c, 0, 0, 0);
}
__device__ __forceinline__ f32x16 zero16() {
    f32x16 z;
    #pragma unroll
    for (int i = 0; i < 16; ++i) z[i] = 0.f;
    return z;
}
__device__ __forceinline__ short8 mk8(unsigned a, unsigned b, unsigned c, unsigned d) {
    uint4 u; u.x = a; u.y = b; u.z = c; u.w = d;
    return __builtin_bit_cast(short8, u);
}

// ---------------- pre-pass: fp32 K,V -> bf16 swizzled LDS tile images in ws --------
// K image: e = row*128 + (col ^ ((row&15)<<3))            holds K[row][col]
// V image: rowp=d>>1; ein=((d&1)<<6)|k;
//          e = rowp*128 + (ein ^ ((rowp&15)<<3))          holds V[k][d]
// Both give ~2-way (free) LDS bank access for the main kernel's b128 reads.
__global__ void __launch_bounds__(256)
prep_kv(const float* __restrict__ Kp, const float* __restrict__ Vp,
        short* __restrict__ wsK, short* __restrict__ wsV)
{
    const int blk = blockIdx.x;          // 0..1023 = bh*32 + kt
    const int bh  = blk >> 5;
    const int kt  = blk & 31;
    const int tid = threadIdx.x;

    const float* Ks = Kp + (size_t)bh * (S_LEN * DH) + (size_t)kt * KVB * DH;
    const float* Vs = Vp + (size_t)bh * (S_LEN * DH) + (size_t)kt * KVB * DH;
    short* dK = wsK + (size_t)blk * TILE_SH;
    short* dV = wsV + (size_t)blk * TILE_SH;

    #pragma unroll
    for (int i = 0; i < 4; ++i) {
        const int e = (tid + 256 * i) * 8;      // dest short index (8 per thread)
        // ---- K ----
        {
            const int row  = e >> 7;
            const int scol = (e & 127) ^ ((row & 15) << 3);
            f32x4 a = *reinterpret_cast<const f32x4*>(Ks + row * DH + scol);
            f32x4 b = *reinterpret_cast<const f32x4*>(Ks + row * DH + scol + 4);
            uint4 u;
            u.x = pk2(a[0], a[1]); u.y = pk2(a[2], a[3]);
            u.z = pk2(b[0], b[1]); u.w = pk2(b[2], b[3]);
            *reinterpret_cast<uint4*>(&dK[e]) = u;
        }
        // ---- V (paired-row transposed image) ----
        {
            const int rowp = e >> 7;                       // d>>1
            const int ein  = (e & 127) ^ ((rowp & 15) << 3);
            const int d    = (rowp << 1) | (ein >> 6);
            const int kb   = ein & 63;                     // 8-aligned
            float t[8];
            #pragma unroll
            for (int m2 = 0; m2 < 8; ++m2)
                t[m2] = Vs[(size_t)(kb + m2) * DH + d];
            uint4 u;
            u.x = pk2(t[0], t[1]); u.y = pk2(t[2], t[3]);
            u.z = pk2(t[4], t[5]); u.w = pk2(t[6], t[7]);
            *reinterpret_cast<uint4*>(&dV[e]) = u;
        }
    }
}

// ---------------- main attention kernel ----------------
// 256 blocks (1/CU), 8 waves each. Waves 0-3: strip qt=j; waves 4-7: strip qt=15-j.
// Both strips consume the SAME kv-tile stream (tiles 0..2(16-j)-1); staging is
// amortized over 2x compute and every SIMD holds 2 waves (TLP). Triple-buffered
// LDS with depth-2 prefetch and counted vmcnt (never drained to 0 mid-loop).
__global__ void __launch_bounds__(512, 2)
attn_fwd(const float* __restrict__ Qp, const short* __restrict__ wsK,
         const short* __restrict__ wsV, float* __restrict__ Op)
{
    __shared__ __align__(16) short ksm[3][TILE_SH];   // 48 KB
    __shared__ __align__(16) short vtm[3][TILE_SH];   // 48 KB

    const int c   = blockIdx.x;        // 0..255; XCD = c%8 = bh%8 (L2 locality)
    const int bh  = c & 31;
    const int j   = c >> 5;            // strip pair 0..7
    const int tid = threadIdx.x;
    const int w   = tid >> 6;
    const int l   = tid & 63;
    const int r31 = l & 31;
    const int hi  = l >> 5;

    const size_t base = (size_t)bh * (S_LEN * DH);
    const short* Kt = wsK + (size_t)bh * NKT * TILE_SH;
    const short* Vt = wsV + (size_t)bh * NKT * TILE_SH;

    const int qt  = (w < 4) ? j : (NQT - 1 - j);
    const int qw  = qt * QT + 32 * (w & 3);   // wave's first q row
    const int qg  = qw + r31;                 // lane's q row
    const int nkt = 2 * (16 - j);             // shared tile stream length

    const float QS = 0.08838834764831845f * 1.4426950408889634f; // 1/sqrt(128)*log2(e)

    // ---- staging: 512 threads copy two 16KB images (2 gload_lds each per image) ----
    auto stage = [&](int kt2, int b) {
        #pragma unroll
        for (int i = 0; i < 2; ++i) {
            const int off = (w + 8 * i) * 512;             // wave-uniform chunk
            __builtin_amdgcn_global_load_lds(
                (gu32*)(Kt + (size_t)kt2 * TILE_SH + off + l * 8),
                (lu32*)(&ksm[b][off]), 16, 0, 0);
            __builtin_amdgcn_global_load_lds(
                (gu32*)(Vt + (size_t)kt2 * TILE_SH + off + l * 8),
                (lu32*)(&vtm[b][off]), 16, 0, 0);
        }
    };
    auto ldK = [&](const short* ks, int row, int col) -> short8 {
        return *reinterpret_cast<const short8*>(&ks[row * 128 + (col ^ ((row & 15) << 3))]);
    };
    auto ldV = [&](const short* vt, int d, int colk) -> short8 {
        const int rowp = d >> 1;
        const int ein  = ((d & 1) << 6) | colk;
        return *reinterpret_cast<const short8*>(&vt[rowp * 128 + (ein ^ ((rowp & 15) << 3))]);
    };

    // ---- Q fragments (B-operand: col=q=r31, k-elem=8hi+jj per 16-d slice) ----
    short8 qb[8];
    {
        const float* qrow = Qp + base + (size_t)qg * DH + 8 * hi;
        #pragma unroll
        for (int t = 0; t < 8; ++t) {
            f32x4 f0 = *reinterpret_cast<const f32x4*>(qrow + 16 * t);
            f32x4 f1 = *reinterpret_cast<const f32x4*>(qrow + 16 * t + 4);
            qb[t] = mk8(pk2(f0[0] * QS, f0[1] * QS), pk2(f0[2] * QS, f0[3] * QS),
                        pk2(f1[0] * QS, f1[1] * QS), pk2(f1[2] * QS, f1[3] * QS));
        }
    }

    f32x16 acc_o[4];
    #pragma unroll
    for (int i = 0; i < 4; ++i) acc_o[i] = zero16();
    float m_run = -1e30f, l_run = 0.f;

    // ---- prologue: tiles 0 and 1 in flight; wait only for tile 0 ----
    stage(0, 0);
    stage(1, 1);
    asm volatile("s_waitcnt vmcnt(4)" ::: "memory");
    __builtin_amdgcn_s_barrier();
    __builtin_amdgcn_sched_barrier(0);
    int cur = 0;

    for (int kt = 0; kt < nkt; ++kt) {
        const int k0 = kt * KVB;
        const bool has2 = (kt + 2 < nkt);
        if (has2) {
            int b2 = cur + 2; if (b2 >= 3) b2 -= 3;
            stage(kt + 2, b2);                 // depth-2 prefetch
        }

        if (k0 <= qw) {
            const bool useS1 = (k0 < qw);
            const short* ks = ksm[cur];
            const short* vt = vtm[cur];

            // ---- QK^T (swapped): lane q=r31, k=crow(rg,hi) (+32 in s1) ----
            f32x16 s0 = zero16(), s1 = zero16();
            __builtin_amdgcn_s_setprio(1);
            #pragma unroll
            for (int t = 0; t < 8; ++t)
                s0 = mfma32(ldK(ks, r31, 16 * t + 8 * hi), qb[t], s0);
            if (useS1) {
                #pragma unroll
                for (int t = 0; t < 8; ++t)
                    s1 = mfma32(ldK(ks, r31 + 32, 16 * t + 8 * hi), qb[t], s1);
            }
            __builtin_amdgcn_s_setprio(0);

            // ---- causal mask (diagonal tiles only) ----
            if (k0 == qw) {
                #pragma unroll
                for (int rg = 0; rg < 16; ++rg) {
                    const int kl = (rg & 3) + 8 * (rg >> 2) + 4 * hi;
                    if (kl > r31) s0[rg] = -3.0e38f;
                }
            }
            if (useS1 && (k0 + 32 == qw)) {
                #pragma unroll
                for (int rg = 0; rg < 16; ++rg) {
                    const int kl = (rg & 3) + 8 * (rg >> 2) + 4 * hi;
                    if (kl > r31) s1[rg] = -3.0e38f;
                }
            }

            // ---- online softmax (in-register, exp2 domain, defer-max T13) ----
            float tm[16];
            #pragma unroll
            for (int i = 0; i < 16; ++i) tm[i] = useS1 ? fmaxf(s0[i], s1[i]) : s0[i];
            #pragma unroll
            for (int st = 8; st > 0; st >>= 1)
                #pragma unroll
                for (int i = 0; i < st; ++i) tm[i] = fmaxf(tm[i], tm[i + st]);
            const float mt = fmaxf(tm[0], __shfl_xor(tm[0], 32));

            float mn = m_run;
            if (!__all(mt <= m_run + 8.0f)) {
                mn = fmaxf(m_run, mt);
                const float al = exp2f(m_run - mn);
                m_run = mn;
                l_run *= al;
                #pragma unroll
                for (int d0 = 0; d0 < 4; ++d0)
                    #pragma unroll
                    for (int i = 0; i < 16; ++i) acc_o[d0][i] *= al;
            }

            #pragma unroll
            for (int i = 0; i < 16; ++i) s0[i] = exp2f(s0[i] - mn);
            if (useS1) {
                #pragma unroll
                for (int i = 0; i < 16; ++i) s1[i] = exp2f(s1[i] - mn);
            }
            float ts[16];
            #pragma unroll
            for (int i = 0; i < 16; ++i) ts[i] = useS1 ? (s0[i] + s1[i]) : s0[i];
            #pragma unroll
            for (int st = 8; st > 0; st >>= 1)
                #pragma unroll
                for (int i = 0; i < st; ++i) ts[i] += ts[i + st];
            l_run += ts[0] + __shfl_xor(ts[0], 32);

            // ---- P -> bf16 B-fragments (cvt_pk + permlane32_swap T12) ----
            short8 pbs[4];
            auto mkpb = [&](const f32x16& s, short8* out) {
                #pragma unroll
                for (int h = 0; h < 2; ++h) {
                    unsigned a1 = pk2(s[8 * h + 0], s[8 * h + 1]);
                    unsigned a2 = pk2(s[8 * h + 2], s[8 * h + 3]);
                    unsigned b1 = pk2(s[8 * h + 4], s[8 * h + 5]);
                    unsigned b2 = pk2(s[8 * h + 6], s[8 * h + 7]);
                    asm volatile("v_permlane32_swap_b32 %0, %1" : "+v"(a1), "+v"(b1));
                    asm volatile("v_permlane32_swap_b32 %0, %1" : "+v"(a2), "+v"(b2));
                    uint4 u; u.x = a1; u.y = a2; u.z = b1; u.w = b2;
                    out[h] = __builtin_bit_cast(short8, u);
                }
            };
            mkpb(s0, &pbs[0]);
            if (useS1) mkpb(s1, &pbs[2]);

            // ---- PV: O^T = V^T x P^T ----
            __builtin_amdgcn_s_setprio(1);
            #pragma unroll
            for (int d0 = 0; d0 < 4; ++d0) {
                const int vr = 32 * d0 + r31;
                acc_o[d0] = mfma32(ldV(vt, vr, 8 * hi), pbs[0], acc_o[d0]);
                acc_o[d0] = mfma32(ldV(vt, vr, 16 + 8 * hi), pbs[1], acc_o[d0]);
            }
            if (useS1) {
                #pragma unroll
                for (int d0 = 0; d0 < 4; ++d0) {
                    const int vr = 32 * d0 + r31;
                    acc_o[d0] = mfma32(ldV(vt, vr, 32 + 8 * hi), pbs[2], acc_o[d0]);
                    acc_o[d0] = mfma32(ldV(vt, vr, 48 + 8 * hi), pbs[3], acc_o[d0]);
                }
            }
            __builtin_amdgcn_s_setprio(0);
        }

        if (kt + 1 < nkt) {
            if (has2) asm volatile("s_waitcnt vmcnt(4)" ::: "memory");  // kt+1 landed
            else      asm volatile("s_waitcnt vmcnt(0)" ::: "memory");  // tail drain
            __builtin_amdgcn_s_barrier();
            __builtin_amdgcn_sched_barrier(0);
            if (++cur == 3) cur = 0;
        }
    }

    // ---- epilogue: normalize, store fp32 ----
    const float rl = 1.0f / l_run;
    float* orow = Op + base + (size_t)qg * DH;
    #pragma unroll
    for (int d0 = 0; d0 < 4; ++d0) {
        #pragma unroll
        for (int rg = 0; rg < 4; ++rg) {
            f32x4 v;
            v[0] = acc_o[d0][4 * rg + 0] * rl;
            v[1] = acc_o[d0][4 * rg + 1] * rl;
            v[2] = acc_o[d0][4 * rg + 2] * rl;
            v[3] = acc_o[d0][4 * rg + 3] * rl;
            *reinterpret_cast<f32x4*>(orow + 32 * d0 + 8 * rg + 4 * hi) = v;
        }
    }
}

} // namespace

extern "C" void kernel_launch(void* const* d_in, const int* in_sizes, int n_in,
                              void* d_out, int out_size, void* d_ws, size_t ws_size,
                              hipStream_t stream)
{
    const float* Q = (const float*)d_in[0];
    const float* K = (const float*)d_in[1];
    const float* V = (const float*)d_in[2];
    float* O = (float*)d_out;

    short* wsK = (short*)d_ws;                          // 32*32 tiles * 16 KB
    short* wsV = wsK + (size_t)32 * NKT * TILE_SH;      // ws >= 33.6 MB

    hipLaunchKernelGGL(prep_kv, dim3(32 * NKT), dim3(256), 0, stream, K, V, wsK, wsV);
    hipLaunchKernelGGL(attn_fwd, dim3(256), dim3(512), 0, stream, Q, wsK, wsV, O);
}